// Round 1
// 710.585 us; speedup vs baseline: 1.0888x; 1.0888x over previous
//
#include <hip/hip_runtime.h>

static constexpr int B = 8;
static constexpr int C = 32;

// ---------------------------------------------------------------------------
// Compile-time workspace layout (u32 units unless noted).
// cnt[3] | off[3] | rec[3] | list[3] (u16 units)
// R2: 4096, 16384, 65536.  3*B*R2: 98304, 393216, 1572864.
// 3*B*N:  1572864, 786432, 393216.
// ---------------------------------------------------------------------------
static constexpr size_t CNT0 = 0,        CNT1 = 98304,    CNT2 = 491520;
static constexpr size_t CNT_TOTAL = 2064384;
static constexpr size_t OFF0 = 2064384,  OFF1 = 2162688,  OFF2 = 2555904;
static constexpr size_t REC0 = 4128768,  REC1 = 5701632,  REC2 = 6488064;
// u16 units (base = 6881280 u32 * 2)
static constexpr size_t LIST0 = 13762560, LIST1 = 15335424, LIST2 = 16121856;
// output float offsets (3 planes x B x C x R2 per scale)
static constexpr size_t OUT0 = 0, OUT1 = 3145728, OUT2 = 15728640;

// ---------------------------------------------------------------------------
// Index chain (bit-identical to the XLA pipeline verified previously):
// u = x * (1/1.10001f) + 0.5f (separate mul/add, NO fma), clamp [0, 0.99999f],
// trunc(u * res).
// ---------------------------------------------------------------------------
__device__ __forceinline__ void plane_cells(float x, float y, float z, int res,
                                            int idxs[3])
{
#pragma clang fp contract(off)
    constexpr float denomf = (float)(1.0 + 0.1 + 1e-5);
    constexpr float recipf = 1.0f / denomf;
    constexpr float hi     = (float)(1.0 - 1e-5);
    const float rf = (float)res;
    const float tx = x * recipf;
    const float ty = y * recipf;
    const float tz = z * recipf;
    const float ux = fminf(fmaxf(tx + 0.5f, 0.0f), hi);
    const float uy = fminf(fmaxf(ty + 0.5f, 0.0f), hi);
    const float uz = fminf(fmaxf(tz + 0.5f, 0.0f), hi);
    const int ix = (int)(ux * rf);
    const int iy = (int)(uy * rf);
    const int iz = (int)(uz * rf);
    idxs[0] = ix + res * iz;   // "xz"
    idxs[1] = ix + res * iy;   // "xy"
    idxs[2] = iy + res * iz;   // "yz"
}

// ---------------------------------------------------------------------------
// FK1: all 3 scales in one launch.
// blocks: s0 [0,2048) (8 b x 256 blk), s1 [2048,3072) (8x128), s2 [3072,3584) (8x64)
// per point, per plane: rank = atomicAdd(count[cell]), store (cell<<16|rank).
// ---------------------------------------------------------------------------
__global__ __launch_bounds__(256) void fused_count_rank(
    const float* __restrict__ c0, const float* __restrict__ c1,
    const float* __restrict__ c2, unsigned int* __restrict__ ws)
{
    int blk = blockIdx.x;
    const float* coords; int N, res, shift; size_t cntB, recB;
    if (blk < 2048)      { coords = c0; N = 65536; res = 64;  shift = 8; cntB = CNT0; recB = REC0; }
    else if (blk < 3072) { blk -= 2048; coords = c1; N = 32768; res = 128; shift = 7; cntB = CNT1; recB = REC1; }
    else                 { blk -= 3072; coords = c2; N = 16384; res = 256; shift = 6; cntB = CNT2; recB = REC2; }
    const int b = blk >> shift;
    const int p = ((blk & ((1 << shift) - 1)) << 8) + threadIdx.x;
    const size_t pt = (size_t)b * N + p;
    const float x = coords[pt * 3 + 0];
    const float y = coords[pt * 3 + 1];
    const float z = coords[pt * 3 + 2];
    int idxs[3];
    plane_cells(x, y, z, res, idxs);
    const int R2 = res * res;
    unsigned int* cnt = ws + cntB;
    unsigned int* rec = ws + recB;
#pragma unroll
    for (int k = 0; k < 3; ++k) {
        const unsigned int cell = (unsigned int)idxs[k];
        const unsigned int rank =
            atomicAdd(&cnt[((size_t)k * B + b) * R2 + cell], 1u);
        rec[((size_t)k * B + b) * N + p] = (cell << 16) | rank;
    }
}

// ---------------------------------------------------------------------------
// FK2: exclusive prefix sum over each (plane,b) segment. 72 blocks total:
// [0,24) s0 (E=4), [24,48) s1 (E=16), [48,72) s2 (E=64).
// ---------------------------------------------------------------------------
__global__ __launch_bounds__(1024) void fused_scan(unsigned int* __restrict__ ws)
{
    __shared__ unsigned int sdata[1024];
    int blk = blockIdx.x;
    size_t cntB, offB; int R2;
    if (blk < 24)      {              cntB = CNT0; offB = OFF0; R2 = 4096; }
    else if (blk < 48) { blk -= 24;   cntB = CNT1; offB = OFF1; R2 = 16384; }
    else               { blk -= 48;   cntB = CNT2; offB = OFF2; R2 = 65536; }
    const size_t base = (size_t)blk * (size_t)R2;
    const unsigned int* cnt = ws + cntB + base;
    unsigned int* off = ws + offB + base;
    const int E = R2 >> 10;
    const int tid = threadIdx.x;
    unsigned int tsum = 0;
    for (int i = 0; i < E; ++i) tsum += cnt[(size_t)tid * E + i];
    sdata[tid] = tsum;
    __syncthreads();
    for (int d = 1; d < 1024; d <<= 1) {
        unsigned int v = (tid >= d) ? sdata[tid - d] : 0u;
        __syncthreads();
        sdata[tid] += v;
        __syncthreads();
    }
    unsigned int run = sdata[tid] - tsum;       // exclusive prefix of tsums
    for (int i = 0; i < E; ++i) {
        const unsigned int cc = cnt[(size_t)tid * E + i];
        off[(size_t)tid * E + i] = run;
        run += cc;
    }
}

// ---------------------------------------------------------------------------
// FK3: invert: list[offset[cell] + rank] = point id. No atomics.
// blocks: s0 [0,6144) (24 kb x 256), s1 [6144,9216) (24x128), s2 [9216,10752) (24x64)
// ---------------------------------------------------------------------------
__global__ __launch_bounds__(256) void fused_build_list(unsigned int* __restrict__ ws)
{
    int blk = blockIdx.x;
    int N, R2, shift; size_t recB, offB, listB;
    if (blk < 6144)      {              N = 65536; R2 = 4096;  shift = 8; recB = REC0; offB = OFF0; listB = LIST0; }
    else if (blk < 9216) { blk -= 6144; N = 32768; R2 = 16384; shift = 7; recB = REC1; offB = OFF1; listB = LIST1; }
    else                 { blk -= 9216; N = 16384; R2 = 65536; shift = 6; recB = REC2; offB = OFF2; listB = LIST2; }
    const int kb = blk >> shift;
    const int p = ((blk & ((1 << shift) - 1)) << 8) + threadIdx.x;
    const unsigned int* rec = ws + recB;
    const unsigned int* off = ws + offB;
    unsigned short* list = (unsigned short*)ws + listB;
    const unsigned int r = rec[(size_t)kb * N + p];
    const unsigned int cell = r >> 16;
    const unsigned int rank = r & 0xffffu;
    const unsigned int pos = off[(size_t)kb * R2 + cell] + rank;
    list[(size_t)kb * N + pos] = (unsigned short)p;
}

// ---------------------------------------------------------------------------
// FK4: gather + mean + write, all scales. 64 cells/block (8 x 32-lane groups,
// lanes = channels, 8 cells each). cnt/off LDS-staged. Point loop unrolled x4.
// LDS transpose -> coalesced nontemporal writes.
// blocks: s0 [0,1536) (24 kb x 64), s1 [1536,7680) (24x256), s2 [7680,32256) (24x1024)
// ---------------------------------------------------------------------------
__global__ __launch_bounds__(256) void fused_gather_mean(
    const float* __restrict__ f0, const float* __restrict__ f1,
    const float* __restrict__ f2, const unsigned int* __restrict__ ws,
    float* __restrict__ out)
{
    __shared__ float tile[C][64 + 1];
    __shared__ unsigned int s_cnt[64];
    __shared__ unsigned int s_off[64];
    int blk = blockIdx.x;
    const float* feats; int N, R2, shift; size_t cntB, offB, listB, outB;
    if (blk < 1536)      {              feats = f0; N = 65536; R2 = 4096;  shift = 6;  cntB = CNT0; offB = OFF0; listB = LIST0; outB = OUT0; }
    else if (blk < 7680) { blk -= 1536; feats = f1; N = 32768; R2 = 16384; shift = 8;  cntB = CNT1; offB = OFF1; listB = LIST1; outB = OUT1; }
    else                 { blk -= 7680; feats = f2; N = 16384; R2 = 65536; shift = 10; cntB = CNT2; offB = OFF2; listB = LIST2; outB = OUT2; }
    const int kb = blk >> shift;
    const int cellBase = (blk & ((1 << shift) - 1)) << 6;
    const int b = kb & (B - 1);
    const int h  = threadIdx.x >> 5;            // 32-lane group id (0..7)
    const int ch = threadIdx.x & 31;            // channel
    const size_t segBase  = (size_t)kb * R2;
    const size_t listBase = (size_t)kb * N;
    const unsigned short* list = (const unsigned short*)ws + listB;
    const float* frow = feats + (size_t)b * N * C + ch;

    if (threadIdx.x < 64) {
        s_cnt[threadIdx.x] = ws[cntB + segBase + cellBase + threadIdx.x];
        s_off[threadIdx.x] = ws[offB + segBase + cellBase + threadIdx.x];
    }
    __syncthreads();

    for (int i = 0; i < 8; ++i) {
        const int lc = h * 8 + i;
        const unsigned int n = s_cnt[lc];
        const unsigned int o = s_off[lc];
        const unsigned short* lp = list + listBase + o;
        float a = 0.0f;
        unsigned int j = 0;
        for (; j + 4 <= n; j += 4) {
            const int p0 = lp[j + 0];
            const int p1 = lp[j + 1];
            const int p2 = lp[j + 2];
            const int p3 = lp[j + 3];
            const float v0 = frow[(size_t)p0 * C];
            const float v1 = frow[(size_t)p1 * C];
            const float v2 = frow[(size_t)p2 * C];
            const float v3 = frow[(size_t)p3 * C];
            a += (v0 + v1) + (v2 + v3);
        }
        for (; j < n; ++j) a += frow[(size_t)lp[j] * C];
        a /= fmaxf((float)n, 1.0f);
        tile[ch][lc] = a;                       // stride-65: conflict-free
    }
    __syncthreads();
#pragma unroll
    for (int c8 = 0; c8 < 8; ++c8) {
        const int ch2  = c8 * 4 + (threadIdx.x >> 6);
        const int cell = threadIdx.x & 63;
        __builtin_nontemporal_store(
            tile[ch2][cell],
            &out[outB + ((size_t)kb * C + ch2) * R2 + cellBase + cell]);
    }
}

extern "C" void kernel_launch(void* const* d_in, const int* in_sizes, int n_in,
                              void* d_out, int out_size, void* d_ws, size_t ws_size,
                              hipStream_t stream)
{
    const float *f[3], *c[3];
    const bool interleaved = in_sizes[1] < in_sizes[2];
    if (interleaved) {
        f[0] = (const float*)d_in[0]; c[0] = (const float*)d_in[1];
        f[1] = (const float*)d_in[2]; c[1] = (const float*)d_in[3];
        f[2] = (const float*)d_in[4]; c[2] = (const float*)d_in[5];
    } else {
        f[0] = (const float*)d_in[0]; f[1] = (const float*)d_in[1];
        f[2] = (const float*)d_in[2];
        c[0] = (const float*)d_in[3]; c[1] = (const float*)d_in[4];
        c[2] = (const float*)d_in[5];
    }

    unsigned int* ws32 = (unsigned int*)d_ws;
    float* out = (float*)d_out;

    // zero only the count grids (8.3 MB)
    hipMemsetAsync(d_ws, 0, CNT_TOTAL * sizeof(unsigned int), stream);

    fused_count_rank<<<dim3(3584), 256, 0, stream>>>(c[0], c[1], c[2], ws32);
    fused_scan<<<dim3(72), 1024, 0, stream>>>(ws32);
    fused_build_list<<<dim3(10752), 256, 0, stream>>>(ws32);
    fused_gather_mean<<<dim3(32256), 256, 0, stream>>>(f[0], f[1], f[2], ws32, out);
}

// Round 2
// 704.137 us; speedup vs baseline: 1.0988x; 1.0092x over previous
//
#include <hip/hip_runtime.h>

static constexpr int B = 8;
static constexpr int C = 32;

// ---------------------------------------------------------------------------
// Compile-time workspace layout (u32 units unless noted).
// cnt[3] | off[3] | rec[3] | list[3] (u16 units)
// R2: 4096, 16384, 65536.  3*B*R2: 98304, 393216, 1572864.
// 3*B*N:  1572864, 786432, 393216.
// ---------------------------------------------------------------------------
static constexpr size_t CNT0 = 0,        CNT1 = 98304,    CNT2 = 491520;
static constexpr size_t CNT_TOTAL = 2064384;
static constexpr size_t OFF0 = 2064384,  OFF1 = 2162688,  OFF2 = 2555904;
static constexpr size_t REC0 = 4128768,  REC1 = 5701632,  REC2 = 6488064;
// u16 units (base = 6881280 u32 * 2)
static constexpr size_t LIST0 = 13762560, LIST1 = 15335424, LIST2 = 16121856;
// output float offsets (3 planes x B x C x R2 per scale)
static constexpr size_t OUT0 = 0, OUT1 = 3145728, OUT2 = 15728640;

// ---------------------------------------------------------------------------
// Index chain (bit-identical to the XLA pipeline verified previously):
// u = x * (1/1.10001f) + 0.5f (separate mul/add, NO fma), clamp [0, 0.99999f],
// trunc(u * res).
// ---------------------------------------------------------------------------
__device__ __forceinline__ void plane_cells(float x, float y, float z, int res,
                                            int idxs[3])
{
#pragma clang fp contract(off)
    constexpr float denomf = (float)(1.0 + 0.1 + 1e-5);
    constexpr float recipf = 1.0f / denomf;
    constexpr float hi     = (float)(1.0 - 1e-5);
    const float rf = (float)res;
    const float tx = x * recipf;
    const float ty = y * recipf;
    const float tz = z * recipf;
    const float ux = fminf(fmaxf(tx + 0.5f, 0.0f), hi);
    const float uy = fminf(fmaxf(ty + 0.5f, 0.0f), hi);
    const float uz = fminf(fmaxf(tz + 0.5f, 0.0f), hi);
    const int ix = (int)(ux * rf);
    const int iy = (int)(uy * rf);
    const int iz = (int)(uz * rf);
    idxs[0] = ix + res * iz;   // "xz"
    idxs[1] = ix + res * iy;   // "xy"
    idxs[2] = iy + res * iz;   // "yz"
}

// ---------------------------------------------------------------------------
// FK1: all 3 scales in one launch.
// blocks: s0 [0,2048) (8 b x 256 blk), s1 [2048,3072) (8x128), s2 [3072,3584) (8x64)
// ---------------------------------------------------------------------------
__global__ __launch_bounds__(256) void fused_count_rank(
    const float* __restrict__ c0, const float* __restrict__ c1,
    const float* __restrict__ c2, unsigned int* __restrict__ ws)
{
    int blk = blockIdx.x;
    const float* coords; int N, res, shift; size_t cntB, recB;
    if (blk < 2048)      { coords = c0; N = 65536; res = 64;  shift = 8; cntB = CNT0; recB = REC0; }
    else if (blk < 3072) { blk -= 2048; coords = c1; N = 32768; res = 128; shift = 7; cntB = CNT1; recB = REC1; }
    else                 { blk -= 3072; coords = c2; N = 16384; res = 256; shift = 6; cntB = CNT2; recB = REC2; }
    const int b = blk >> shift;
    const int p = ((blk & ((1 << shift) - 1)) << 8) + threadIdx.x;
    const size_t pt = (size_t)b * N + p;
    const float x = coords[pt * 3 + 0];
    const float y = coords[pt * 3 + 1];
    const float z = coords[pt * 3 + 2];
    int idxs[3];
    plane_cells(x, y, z, res, idxs);
    const int R2 = res * res;
    unsigned int* cnt = ws + cntB;
    unsigned int* rec = ws + recB;
#pragma unroll
    for (int k = 0; k < 3; ++k) {
        const unsigned int cell = (unsigned int)idxs[k];
        const unsigned int rank =
            atomicAdd(&cnt[((size_t)k * B + b) * R2 + cell], 1u);
        rec[((size_t)k * B + b) * N + p] = (cell << 16) | rank;
    }
}

// ---------------------------------------------------------------------------
// FK2: exclusive prefix sum over each (plane,b) segment. 72 blocks total.
// ---------------------------------------------------------------------------
__global__ __launch_bounds__(1024) void fused_scan(unsigned int* __restrict__ ws)
{
    __shared__ unsigned int sdata[1024];
    int blk = blockIdx.x;
    size_t cntB, offB; int R2;
    if (blk < 24)      {              cntB = CNT0; offB = OFF0; R2 = 4096; }
    else if (blk < 48) { blk -= 24;   cntB = CNT1; offB = OFF1; R2 = 16384; }
    else               { blk -= 48;   cntB = CNT2; offB = OFF2; R2 = 65536; }
    const size_t base = (size_t)blk * (size_t)R2;
    const unsigned int* cnt = ws + cntB + base;
    unsigned int* off = ws + offB + base;
    const int E = R2 >> 10;
    const int tid = threadIdx.x;
    unsigned int tsum = 0;
    for (int i = 0; i < E; ++i) tsum += cnt[(size_t)tid * E + i];
    sdata[tid] = tsum;
    __syncthreads();
    for (int d = 1; d < 1024; d <<= 1) {
        unsigned int v = (tid >= d) ? sdata[tid - d] : 0u;
        __syncthreads();
        sdata[tid] += v;
        __syncthreads();
    }
    unsigned int run = sdata[tid] - tsum;       // exclusive prefix of tsums
    for (int i = 0; i < E; ++i) {
        const unsigned int cc = cnt[(size_t)tid * E + i];
        off[(size_t)tid * E + i] = run;
        run += cc;
    }
}

// ---------------------------------------------------------------------------
// FK3: invert: list[offset[cell] + rank] = point id. No atomics.
// ---------------------------------------------------------------------------
__global__ __launch_bounds__(256) void fused_build_list(unsigned int* __restrict__ ws)
{
    int blk = blockIdx.x;
    int N, R2, shift; size_t recB, offB, listB;
    if (blk < 6144)      {              N = 65536; R2 = 4096;  shift = 8; recB = REC0; offB = OFF0; listB = LIST0; }
    else if (blk < 9216) { blk -= 6144; N = 32768; R2 = 16384; shift = 7; recB = REC1; offB = OFF1; listB = LIST1; }
    else                 { blk -= 9216; N = 16384; R2 = 65536; shift = 6; recB = REC2; offB = OFF2; listB = LIST2; }
    const int kb = blk >> shift;
    const int p = ((blk & ((1 << shift) - 1)) << 8) + threadIdx.x;
    const unsigned int* rec = ws + recB;
    const unsigned int* off = ws + offB;
    unsigned short* list = (unsigned short*)ws + listB;
    const unsigned int r = rec[(size_t)kb * N + p];
    const unsigned int cell = r >> 16;
    const unsigned int rank = r & 0xffffu;
    const unsigned int pos = off[(size_t)kb * R2 + cell] + rank;
    list[(size_t)kb * N + pos] = (unsigned short)p;
}

// ---------------------------------------------------------------------------
// FK4 v2: gather + mean + write, all scales. 64 cells/block, 8 x 32-lane
// groups, one cell-octet per group. Lane remap inside a group:
//   sub = (tid>>3)&3  -> point slot (4 points in flight)
//   chq = tid&7       -> float4 channel quad (chq*4 .. chq*4+3)
// Main loop: 2x unroll -> 8 independent 16B loads in flight per group.
// Cross-slot reduce via __shfl_xor(8/16) (stays inside the 32-lane group).
// LDS transpose -> coalesced nontemporal writes (zeros for empty cells).
// ---------------------------------------------------------------------------
__global__ __launch_bounds__(256) void fused_gather_mean(
    const float* __restrict__ f0, const float* __restrict__ f1,
    const float* __restrict__ f2, const unsigned int* __restrict__ ws,
    float* __restrict__ out)
{
    __shared__ float tile[C][64 + 1];
    __shared__ unsigned int s_cnt[64];
    __shared__ unsigned int s_off[64];
    int blk = blockIdx.x;
    const float* feats; int N, R2, shift; size_t cntB, offB, listB, outB;
    if (blk < 1536)      {              feats = f0; N = 65536; R2 = 4096;  shift = 6;  cntB = CNT0; offB = OFF0; listB = LIST0; outB = OUT0; }
    else if (blk < 7680) { blk -= 1536; feats = f1; N = 32768; R2 = 16384; shift = 8;  cntB = CNT1; offB = OFF1; listB = LIST1; outB = OUT1; }
    else                 { blk -= 7680; feats = f2; N = 16384; R2 = 65536; shift = 10; cntB = CNT2; offB = OFF2; listB = LIST2; outB = OUT2; }
    const int kb = blk >> shift;
    const int cellBase = (blk & ((1 << shift) - 1)) << 6;
    const int b = kb & (B - 1);
    const int h   = threadIdx.x >> 5;        // 32-lane group id (0..7)
    const int sub = (threadIdx.x >> 3) & 3;  // point slot
    const int chq = threadIdx.x & 7;         // float4 channel quad
    const size_t segBase  = (size_t)kb * R2;
    const size_t listBase = (size_t)kb * N;
    const unsigned short* list = (const unsigned short*)ws + listB;
    const float4* frow4 = (const float4*)(feats + (size_t)b * N * C) + chq;

    if (threadIdx.x < 64) {
        s_cnt[threadIdx.x] = ws[cntB + segBase + cellBase + threadIdx.x];
        s_off[threadIdx.x] = ws[offB + segBase + cellBase + threadIdx.x];
    }
    __syncthreads();

    for (int i = 0; i < 8; ++i) {
        const int lc = h * 8 + i;
        const unsigned int n = s_cnt[lc];
        const unsigned short* lp = list + listBase + s_off[lc];
        float ax = 0.0f, ay = 0.0f, az = 0.0f, aw = 0.0f;
        unsigned int j = 0;
        for (; j + 8 <= n; j += 8) {
            const int pA = lp[j + sub];
            const int pB = lp[j + 4 + sub];
            const float4 vA = frow4[(size_t)pA * 8];
            const float4 vB = frow4[(size_t)pB * 8];
            ax += vA.x + vB.x; ay += vA.y + vB.y;
            az += vA.z + vB.z; aw += vA.w + vB.w;
        }
        if (j + sub < n) {
            const float4 v = frow4[(size_t)lp[j + sub] * 8];
            ax += v.x; ay += v.y; az += v.z; aw += v.w;
        }
        if (j + 4 + sub < n) {
            const float4 v = frow4[(size_t)lp[j + 4 + sub] * 8];
            ax += v.x; ay += v.y; az += v.z; aw += v.w;
        }
        // reduce the 4 point slots: lanes xor 8, then xor 16 (within group)
        ax += __shfl_xor(ax, 8);  ay += __shfl_xor(ay, 8);
        az += __shfl_xor(az, 8);  aw += __shfl_xor(aw, 8);
        ax += __shfl_xor(ax, 16); ay += __shfl_xor(ay, 16);
        az += __shfl_xor(az, 16); aw += __shfl_xor(aw, 16);
        if (sub == 0) {
            const float d = fmaxf((float)n, 1.0f);
            tile[chq * 4 + 0][lc] = ax / d;
            tile[chq * 4 + 1][lc] = ay / d;
            tile[chq * 4 + 2][lc] = az / d;
            tile[chq * 4 + 3][lc] = aw / d;
        }
    }
    __syncthreads();
#pragma unroll
    for (int c8 = 0; c8 < 8; ++c8) {
        const int ch2  = c8 * 4 + (threadIdx.x >> 6);
        const int cell = threadIdx.x & 63;
        __builtin_nontemporal_store(
            tile[ch2][cell],
            &out[outB + ((size_t)kb * C + ch2) * R2 + cellBase + cell]);
    }
}

extern "C" void kernel_launch(void* const* d_in, const int* in_sizes, int n_in,
                              void* d_out, int out_size, void* d_ws, size_t ws_size,
                              hipStream_t stream)
{
    const float *f[3], *c[3];
    const bool interleaved = in_sizes[1] < in_sizes[2];
    if (interleaved) {
        f[0] = (const float*)d_in[0]; c[0] = (const float*)d_in[1];
        f[1] = (const float*)d_in[2]; c[1] = (const float*)d_in[3];
        f[2] = (const float*)d_in[4]; c[2] = (const float*)d_in[5];
    } else {
        f[0] = (const float*)d_in[0]; f[1] = (const float*)d_in[1];
        f[2] = (const float*)d_in[2];
        c[0] = (const float*)d_in[3]; c[1] = (const float*)d_in[4];
        c[2] = (const float*)d_in[5];
    }

    unsigned int* ws32 = (unsigned int*)d_ws;
    float* out = (float*)d_out;

    // zero only the count grids (8.3 MB)
    hipMemsetAsync(d_ws, 0, CNT_TOTAL * sizeof(unsigned int), stream);

    fused_count_rank<<<dim3(3584), 256, 0, stream>>>(c[0], c[1], c[2], ws32);
    fused_scan<<<dim3(72), 1024, 0, stream>>>(ws32);
    fused_build_list<<<dim3(10752), 256, 0, stream>>>(ws32);
    fused_gather_mean<<<dim3(32256), 256, 0, stream>>>(f[0], f[1], f[2], ws32, out);
}

// Round 3
// 616.156 us; speedup vs baseline: 1.2557x; 1.1428x over previous
//
#include <hip/hip_runtime.h>

static constexpr int B = 8;
static constexpr int C = 32;

// ---------------------------------------------------------------------------
// Compile-time workspace layout (u32 units unless noted).
// cnt[3] | off[3] | rec[3] | list[3] (u16 units)
// ---------------------------------------------------------------------------
static constexpr size_t CNT0 = 0,        CNT1 = 98304,    CNT2 = 491520;
static constexpr size_t CNT_TOTAL = 2064384;
static constexpr size_t OFF0 = 2064384,  OFF1 = 2162688,  OFF2 = 2555904;
static constexpr size_t REC0 = 4128768,  REC1 = 5701632,  REC2 = 6488064;
// u16 units (base = 6881280 u32 * 2)
static constexpr size_t LIST0 = 13762560, LIST1 = 15335424, LIST2 = 16121856;
// output float offsets (3 planes x B x C x R2 per scale)
static constexpr size_t OUT0 = 0, OUT1 = 3145728, OUT2 = 15728640;

// ---------------------------------------------------------------------------
// Index chain (bit-identical to the XLA pipeline verified previously).
// ---------------------------------------------------------------------------
__device__ __forceinline__ void plane_cells(float x, float y, float z, int res,
                                            int idxs[3])
{
#pragma clang fp contract(off)
    constexpr float denomf = (float)(1.0 + 0.1 + 1e-5);
    constexpr float recipf = 1.0f / denomf;
    constexpr float hi     = (float)(1.0 - 1e-5);
    const float rf = (float)res;
    const float tx = x * recipf;
    const float ty = y * recipf;
    const float tz = z * recipf;
    const float ux = fminf(fmaxf(tx + 0.5f, 0.0f), hi);
    const float uy = fminf(fmaxf(ty + 0.5f, 0.0f), hi);
    const float uz = fminf(fmaxf(tz + 0.5f, 0.0f), hi);
    const int ix = (int)(ux * rf);
    const int iy = (int)(uy * rf);
    const int iz = (int)(uz * rf);
    idxs[0] = ix + res * iz;   // "xz"
    idxs[1] = ix + res * iy;   // "xy"
    idxs[2] = iy + res * iz;   // "yz"
}

// ---------------------------------------------------------------------------
// FK1: all 3 scales in one launch.
// ---------------------------------------------------------------------------
__global__ __launch_bounds__(256) void fused_count_rank(
    const float* __restrict__ c0, const float* __restrict__ c1,
    const float* __restrict__ c2, unsigned int* __restrict__ ws)
{
    int blk = blockIdx.x;
    const float* coords; int N, res, shift; size_t cntB, recB;
    if (blk < 2048)      { coords = c0; N = 65536; res = 64;  shift = 8; cntB = CNT0; recB = REC0; }
    else if (blk < 3072) { blk -= 2048; coords = c1; N = 32768; res = 128; shift = 7; cntB = CNT1; recB = REC1; }
    else                 { blk -= 3072; coords = c2; N = 16384; res = 256; shift = 6; cntB = CNT2; recB = REC2; }
    const int b = blk >> shift;
    const int p = ((blk & ((1 << shift) - 1)) << 8) + threadIdx.x;
    const size_t pt = (size_t)b * N + p;
    const float x = coords[pt * 3 + 0];
    const float y = coords[pt * 3 + 1];
    const float z = coords[pt * 3 + 2];
    int idxs[3];
    plane_cells(x, y, z, res, idxs);
    const int R2 = res * res;
    unsigned int* cnt = ws + cntB;
    unsigned int* rec = ws + recB;
#pragma unroll
    for (int k = 0; k < 3; ++k) {
        const unsigned int cell = (unsigned int)idxs[k];
        const unsigned int rank =
            atomicAdd(&cnt[((size_t)k * B + b) * R2 + cell], 1u);
        rec[((size_t)k * B + b) * N + p] = (cell << 16) | rank;
    }
}

// ---------------------------------------------------------------------------
// FK2 v2: exclusive prefix sum per (plane,b) segment. 72 blocks.
// uint4 vectorized load/store (4x fewer VMEM instrs on this latency-bound,
// 72-block launch).
// ---------------------------------------------------------------------------
__global__ __launch_bounds__(1024) void fused_scan(unsigned int* __restrict__ ws)
{
    __shared__ unsigned int sdata[1024];
    int blk = blockIdx.x;
    size_t cntB, offB; int R2;
    if (blk < 24)      {              cntB = CNT0; offB = OFF0; R2 = 4096; }
    else if (blk < 48) { blk -= 24;   cntB = CNT1; offB = OFF1; R2 = 16384; }
    else               { blk -= 48;   cntB = CNT2; offB = OFF2; R2 = 65536; }
    const size_t base = (size_t)blk * (size_t)R2;
    const uint4* cnt4 = (const uint4*)(ws + cntB + base);
    uint4* off4 = (uint4*)(ws + offB + base);
    const int E4 = R2 >> 12;                   // uint4 elems per thread
    const int tid = threadIdx.x;
    unsigned int tsum = 0;
    for (int i = 0; i < E4; ++i) {
        const uint4 cc = cnt4[tid * E4 + i];
        tsum += cc.x + cc.y + cc.z + cc.w;
    }
    sdata[tid] = tsum;
    __syncthreads();
    for (int d = 1; d < 1024; d <<= 1) {
        unsigned int v = (tid >= d) ? sdata[tid - d] : 0u;
        __syncthreads();
        sdata[tid] += v;
        __syncthreads();
    }
    unsigned int run = sdata[tid] - tsum;       // exclusive prefix of tsums
    for (int i = 0; i < E4; ++i) {
        const uint4 cc = cnt4[tid * E4 + i];
        uint4 o;
        o.x = run; run += cc.x;
        o.y = run; run += cc.y;
        o.z = run; run += cc.z;
        o.w = run; run += cc.w;
        off4[tid * E4 + i] = o;
    }
}

// ---------------------------------------------------------------------------
// FK3: invert: list[offset[cell] + rank] = point id. No atomics.
// ---------------------------------------------------------------------------
__global__ __launch_bounds__(256) void fused_build_list(unsigned int* __restrict__ ws)
{
    int blk = blockIdx.x;
    int N, R2, shift; size_t recB, offB, listB;
    if (blk < 6144)      {              N = 65536; R2 = 4096;  shift = 8; recB = REC0; offB = OFF0; listB = LIST0; }
    else if (blk < 9216) { blk -= 6144; N = 32768; R2 = 16384; shift = 7; recB = REC1; offB = OFF1; listB = LIST1; }
    else                 { blk -= 9216; N = 16384; R2 = 65536; shift = 6; recB = REC2; offB = OFF2; listB = LIST2; }
    const int kb = blk >> shift;
    const int p = ((blk & ((1 << shift) - 1)) << 8) + threadIdx.x;
    const unsigned int* rec = ws + recB;
    const unsigned int* off = ws + offB;
    unsigned short* list = (unsigned short*)ws + listB;
    const unsigned int r = rec[(size_t)kb * N + p];
    const unsigned int cell = r >> 16;
    const unsigned int rank = r & 0xffffu;
    const unsigned int pos = off[(size_t)kb * R2 + cell] + rank;
    list[(size_t)kb * N + pos] = (unsigned short)p;
}

// ---------------------------------------------------------------------------
// FK4 v3: gather + mean + write. 64 cells/block, 8 x 32-lane groups.
//   sub = (tid>>3)&3 -> point slot, chq = tid&7 -> float4 channel quad.
// v3 changes: n==0 fast path (78% of s2 cells skip the whole epilogue),
// rcp+mul instead of 4 IEEE divides, 32-bit byte-offset saddr addressing.
// ---------------------------------------------------------------------------
__global__ __launch_bounds__(256) void fused_gather_mean(
    const float* __restrict__ f0, const float* __restrict__ f1,
    const float* __restrict__ f2, const unsigned int* __restrict__ ws,
    float* __restrict__ out)
{
    __shared__ float tile[C][64 + 1];
    __shared__ unsigned int s_cnt[64];
    __shared__ unsigned int s_off[64];
    int blk = blockIdx.x;
    const float* feats; int N, R2, shift; size_t cntB, offB, listB, outB;
    if (blk < 1536)      {              feats = f0; N = 65536; R2 = 4096;  shift = 6;  cntB = CNT0; offB = OFF0; listB = LIST0; outB = OUT0; }
    else if (blk < 7680) { blk -= 1536; feats = f1; N = 32768; R2 = 16384; shift = 8;  cntB = CNT1; offB = OFF1; listB = LIST1; outB = OUT1; }
    else                 { blk -= 7680; feats = f2; N = 16384; R2 = 65536; shift = 10; cntB = CNT2; offB = OFF2; listB = LIST2; outB = OUT2; }
    const int kb = blk >> shift;
    const int cellBase = (blk & ((1 << shift) - 1)) << 6;
    const int b = kb & (B - 1);
    const int h   = threadIdx.x >> 5;        // 32-lane group id (0..7)
    const int sub = (threadIdx.x >> 3) & 3;  // point slot
    const int chq = threadIdx.x & 7;         // float4 channel quad
    const size_t segBase  = (size_t)kb * R2;
    const size_t listBase = (size_t)kb * N;
    const unsigned short* list = (const unsigned short*)ws + listB;
    const char* fB = (const char*)(feats + (size_t)b * N * C);  // wave-uniform
    const unsigned int laneOff = (unsigned int)chq << 4;        // chq*16 bytes

    if (threadIdx.x < 64) {
        s_cnt[threadIdx.x] = ws[cntB + segBase + cellBase + threadIdx.x];
        s_off[threadIdx.x] = ws[offB + segBase + cellBase + threadIdx.x];
    }
    __syncthreads();

    for (int i = 0; i < 8; ++i) {
        const int lc = h * 8 + i;
        const unsigned int n = s_cnt[lc];
        if (n == 0u) {                       // empty cell: zeros, no epilogue
            if (sub == 0) {
                tile[chq * 4 + 0][lc] = 0.0f;
                tile[chq * 4 + 1][lc] = 0.0f;
                tile[chq * 4 + 2][lc] = 0.0f;
                tile[chq * 4 + 3][lc] = 0.0f;
            }
            continue;
        }
        const unsigned short* lp = list + listBase + s_off[lc];
        float ax = 0.0f, ay = 0.0f, az = 0.0f, aw = 0.0f;
        unsigned int j = 0;
        for (; j + 8 <= n; j += 8) {
            const unsigned int oA = ((unsigned int)lp[j + sub]     << 7) + laneOff;
            const unsigned int oB = ((unsigned int)lp[j + 4 + sub] << 7) + laneOff;
            const float4 vA = *(const float4*)(fB + oA);
            const float4 vB = *(const float4*)(fB + oB);
            ax += vA.x + vB.x; ay += vA.y + vB.y;
            az += vA.z + vB.z; aw += vA.w + vB.w;
        }
        if (j + sub < n) {
            const unsigned int o = ((unsigned int)lp[j + sub] << 7) + laneOff;
            const float4 v = *(const float4*)(fB + o);
            ax += v.x; ay += v.y; az += v.z; aw += v.w;
        }
        if (j + 4 + sub < n) {
            const unsigned int o = ((unsigned int)lp[j + 4 + sub] << 7) + laneOff;
            const float4 v = *(const float4*)(fB + o);
            ax += v.x; ay += v.y; az += v.z; aw += v.w;
        }
        // reduce the 4 point slots (within the 32-lane group)
        ax += __shfl_xor(ax, 8);  ay += __shfl_xor(ay, 8);
        az += __shfl_xor(az, 8);  aw += __shfl_xor(aw, 8);
        ax += __shfl_xor(ax, 16); ay += __shfl_xor(ay, 16);
        az += __shfl_xor(az, 16); aw += __shfl_xor(aw, 16);
        if (sub == 0) {
            const float r = __builtin_amdgcn_rcpf((float)n);   // n >= 1
            tile[chq * 4 + 0][lc] = ax * r;
            tile[chq * 4 + 1][lc] = ay * r;
            tile[chq * 4 + 2][lc] = az * r;
            tile[chq * 4 + 3][lc] = aw * r;
        }
    }
    __syncthreads();
#pragma unroll
    for (int c8 = 0; c8 < 8; ++c8) {
        const int ch2  = c8 * 4 + (threadIdx.x >> 6);
        const int cell = threadIdx.x & 63;
        __builtin_nontemporal_store(
            tile[ch2][cell],
            &out[outB + ((size_t)kb * C + ch2) * R2 + cellBase + cell]);
    }
}

extern "C" void kernel_launch(void* const* d_in, const int* in_sizes, int n_in,
                              void* d_out, int out_size, void* d_ws, size_t ws_size,
                              hipStream_t stream)
{
    const float *f[3], *c[3];
    const bool interleaved = in_sizes[1] < in_sizes[2];
    if (interleaved) {
        f[0] = (const float*)d_in[0]; c[0] = (const float*)d_in[1];
        f[1] = (const float*)d_in[2]; c[1] = (const float*)d_in[3];
        f[2] = (const float*)d_in[4]; c[2] = (const float*)d_in[5];
    } else {
        f[0] = (const float*)d_in[0]; f[1] = (const float*)d_in[1];
        f[2] = (const float*)d_in[2];
        c[0] = (const float*)d_in[3]; c[1] = (const float*)d_in[4];
        c[2] = (const float*)d_in[5];
    }

    unsigned int* ws32 = (unsigned int*)d_ws;
    float* out = (float*)d_out;

    // zero only the count grids (8.3 MB)
    hipMemsetAsync(d_ws, 0, CNT_TOTAL * sizeof(unsigned int), stream);

    fused_count_rank<<<dim3(3584), 256, 0, stream>>>(c[0], c[1], c[2], ws32);
    fused_scan<<<dim3(72), 1024, 0, stream>>>(ws32);
    fused_build_list<<<dim3(10752), 256, 0, stream>>>(ws32);
    fused_gather_mean<<<dim3(32256), 256, 0, stream>>>(f[0], f[1], f[2], ws32, out);
}